// Round 15
// baseline (553.318 us; speedup 1.0000x reference)
//
#include <hip/hip_runtime.h>
#include <math.h>

#define VOCAB 500
#define EMB   64
#define HID   64
#define BB    512
#define TT    512
#define RB    2            // batch rows per block (per-wave ILP)
#define KC    4            // steps per chunk (barrier period)
#define NC    (TT / KC)    // 128 chunks

// tanh(x) = sign(x) * (1 - 2e/(1+e)), e = exp(-2|x|)  (stable, ~1e-6 abs err)
__device__ __forceinline__ float fast_tanh(float x) {
    float ax = fabsf(x);
    float e  = __expf(-2.0f * ax);
    float r  = __builtin_amdgcn_rcpf(1.0f + e);
    float t  = fmaf(-2.0f * e, r, 1.0f);
    return copysignf(t, x);
}

// in-wave broadcast of lane `lane`'s value (compile-time lane) via v_readlane
__device__ __forceinline__ float bcast(float v, int lane) {
    return __int_as_float(__builtin_amdgcn_readlane(__float_as_int(v), lane));
}

// proj[v][j] = b_ih0[j] + sum_k W_ih0[j][k] * emb[v][k]
__global__ __launch_bounds__(64) void proj_kernel(
        const float* __restrict__ emb,
        const float* __restrict__ W_ih0,
        const float* __restrict__ b_ih0,
        float* __restrict__ proj) {
    const int v = blockIdx.x;
    const int j = threadIdx.x;
    const float4* e4 = (const float4*)(emb + v * EMB);
    const float4* w4 = (const float4*)(W_ih0 + j * EMB);
    float acc = b_ih0[j];
    #pragma unroll
    for (int k = 0; k < EMB / 4; ++k) {
        float4 e = e4[k];
        float4 w = w4[k];
        acc = fmaf(w.x, e.x, acc);
        acc = fmaf(w.y, e.y, acc);
        acc = fmaf(w.z, e.z, acc);
        acc = fmaf(w.w, e.w, acc);
    }
    proj[v * HID + j] = acc;
}

// Chunked pipeline, 3 waves/block, RB=2 rows/block, barrier per KC steps.
//   wave0: h1 recurrence, chunk c, rows A,B interleaved (readlane broadcast)
//   wave1: A = W_ih1 . h1, chunk c-1 (per-lane ds_read + readlane broadcast)
//   wave2: h2 recurrence, chunk c-2
// Ring parities (as round 12, verified): wave0 W H1R[c&1], wave1 R H1R[(c-1)&1]
// W AAR[(c-1)&1], wave2 R AAR[c&1] (== (c-2)&1).
__global__ __launch_bounds__(192, 1) void rnn_kernel(
        const int*   __restrict__ x,
        const float* __restrict__ proj,
        const float* __restrict__ W_hh0,
        const float* __restrict__ b_hh0,
        const float* __restrict__ W_ih1,
        const float* __restrict__ W_hh1,
        const float* __restrict__ b_ih1,
        const float* __restrict__ b_hh1,
        const float* __restrict__ fc_w,
        const float* __restrict__ fc_b,
        float* __restrict__ out) {
    const int b0  = blockIdx.x * RB;   // rows b0, b0+1
    const int tid = threadIdx.x;
    const int wid = tid >> 6;          // 0,1,2 (wave-uniform)
    const int j   = tid & 63;          // hidden unit

    __shared__ __align__(16) float H1R[2][KC][RB][HID];
    __shared__ __align__(16) float AAR[2][KC][RB][HID];
    __shared__ int xls[RB][TT];

    // stage both rows' token indices (rows contiguous in x)
    for (int t = tid; t < RB * TT; t += 192)
        ((int*)xls)[t] = x[b0 * TT + t];

    // each wave loads ONE weight row into registers (shared by both rows)
    const float* wsrc = (wid == 0 ? W_hh0 : (wid == 1 ? W_ih1 : W_hh1)) + j * HID;
    float w[HID];
    {
        const float4* w4 = (const float4*)wsrc;
        #pragma unroll
        for (int k = 0; k < HID / 4; ++k) {
            float4 t4 = w4[k];
            w[4*k+0] = t4.x; w[4*k+1] = t4.y; w[4*k+2] = t4.z; w[4*k+3] = t4.w;
        }
    }
    #pragma unroll
    for (int k = 0; k < HID; ++k) asm volatile("" : "+v"(w[k]));

    const float bh0 = b_hh0[j];
    const float bi1 = b_ih1[j] + b_hh1[j];
    const float fcw = fc_w[j];

    __syncthreads();   // xls visible

    float h1A = 0.0f, h1B = 0.0f, h2A = 0.0f, h2B = 0.0f;
    float xinA[KC], xinB[KC], xnA[KC], xnB[KC];
    if (wid == 0) {
        #pragma unroll
        for (int u = 0; u < KC; ++u) {
            xinA[u] = proj[xls[0][u] * HID + j];
            xinB[u] = proj[xls[1][u] * HID + j];
        }
    }

    for (int c = 0; c < NC + 2; ++c) {
        if (wid == 0) {
            if (c < NC) {
                const int base = ((c + 1) & (NC - 1)) * KC;
                #pragma unroll
                for (int u = 0; u < KC; ++u) {
                    xnA[u] = proj[xls[0][base + u] * HID + j];
                    xnB[u] = proj[xls[1][base + u] * HID + j];
                }
                #pragma unroll
                for (int u = 0; u < KC; ++u) {
                    float aA0 = xinA[u] + bh0, aA1 = 0.0f, aA2 = 0.0f, aA3 = 0.0f;
                    float aB0 = xinB[u] + bh0, aB1 = 0.0f, aB2 = 0.0f, aB3 = 0.0f;
                    #pragma unroll
                    for (int k = 0; k < HID; k += 4) {
                        aA0 = fmaf(w[k+0], bcast(h1A, k+0), aA0);
                        aB0 = fmaf(w[k+0], bcast(h1B, k+0), aB0);
                        aA1 = fmaf(w[k+1], bcast(h1A, k+1), aA1);
                        aB1 = fmaf(w[k+1], bcast(h1B, k+1), aB1);
                        aA2 = fmaf(w[k+2], bcast(h1A, k+2), aA2);
                        aB2 = fmaf(w[k+2], bcast(h1B, k+2), aB2);
                        aA3 = fmaf(w[k+3], bcast(h1A, k+3), aA3);
                        aB3 = fmaf(w[k+3], bcast(h1B, k+3), aB3);
                    }
                    h1A = fast_tanh((aA0 + aA1) + (aA2 + aA3));
                    h1B = fast_tanh((aB0 + aB1) + (aB2 + aB3));
                    H1R[c & 1][u][0][j] = h1A;
                    H1R[c & 1][u][1][j] = h1B;
                    xinA[u] = xnA[u];
                    xinB[u] = xnB[u];
                }
            }
        } else if (wid == 1) {
            if (c >= 1 && c <= NC) {
                const int p = (c - 1) & 1;
                #pragma unroll
                for (int u = 0; u < KC; ++u) {
                    const float vA = H1R[p][u][0][j];   // per-lane read
                    const float vB = H1R[p][u][1][j];
                    float aA0 = 0.0f, aA1 = 0.0f, aA2 = 0.0f, aA3 = 0.0f;
                    float aB0 = 0.0f, aB1 = 0.0f, aB2 = 0.0f, aB3 = 0.0f;
                    #pragma unroll
                    for (int k = 0; k < HID; k += 4) {
                        aA0 = fmaf(w[k+0], bcast(vA, k+0), aA0);
                        aB0 = fmaf(w[k+0], bcast(vB, k+0), aB0);
                        aA1 = fmaf(w[k+1], bcast(vA, k+1), aA1);
                        aB1 = fmaf(w[k+1], bcast(vB, k+1), aB1);
                        aA2 = fmaf(w[k+2], bcast(vA, k+2), aA2);
                        aB2 = fmaf(w[k+2], bcast(vB, k+2), aB2);
                        aA3 = fmaf(w[k+3], bcast(vA, k+3), aA3);
                        aB3 = fmaf(w[k+3], bcast(vB, k+3), aB3);
                    }
                    AAR[p][u][0][j] = (aA0 + aA1) + (aA2 + aA3);
                    AAR[p][u][1][j] = (aB0 + aB1) + (aB2 + aB3);
                }
            }
        } else {
            if (c >= 2) {
                const int p = c & 1;        // == (c-2)&1
                #pragma unroll
                for (int u = 0; u < KC; ++u) {
                    float aA0 = AAR[p][u][0][j] + bi1, aA1 = 0.0f, aA2 = 0.0f, aA3 = 0.0f;
                    float aB0 = AAR[p][u][1][j] + bi1, aB1 = 0.0f, aB2 = 0.0f, aB3 = 0.0f;
                    #pragma unroll
                    for (int k = 0; k < HID; k += 4) {
                        aA0 = fmaf(w[k+0], bcast(h2A, k+0), aA0);
                        aB0 = fmaf(w[k+0], bcast(h2B, k+0), aB0);
                        aA1 = fmaf(w[k+1], bcast(h2A, k+1), aA1);
                        aB1 = fmaf(w[k+1], bcast(h2B, k+1), aB1);
                        aA2 = fmaf(w[k+2], bcast(h2A, k+2), aA2);
                        aB2 = fmaf(w[k+2], bcast(h2B, k+2), aB2);
                        aA3 = fmaf(w[k+3], bcast(h2A, k+3), aA3);
                        aB3 = fmaf(w[k+3], bcast(h2B, k+3), aB3);
                    }
                    h2A = fast_tanh((aA0 + aA1) + (aA2 + aA3));
                    h2B = fast_tanh((aB0 + aB1) + (aB2 + aB3));
                }
            }
        }
        __syncthreads();
    }

    // out[b0+r] = fc_b + sum_j h2[r][j] * fc_w[j]   (wave2 holds h2A/h2B)
    if (wid == 2) {
        float vA = h2A * fcw;
        float vB = h2B * fcw;
        #pragma unroll
        for (int o = 32; o > 0; o >>= 1) {
            vA += __shfl_down(vA, o, 64);
            vB += __shfl_down(vB, o, 64);
        }
        if (j == 0) {
            out[b0 + 0] = vA + fc_b[0];
            out[b0 + 1] = vB + fc_b[0];
        }
    }
}

extern "C" void kernel_launch(void* const* d_in, const int* in_sizes, int n_in,
                              void* d_out, int out_size, void* d_ws, size_t ws_size,
                              hipStream_t stream) {
    const int*   x     = (const int*)  d_in[0];
    const float* emb   = (const float*)d_in[1];
    const float* W_ih0 = (const float*)d_in[2];
    const float* W_hh0 = (const float*)d_in[3];
    const float* b_ih0 = (const float*)d_in[4];
    const float* b_hh0 = (const float*)d_in[5];
    const float* W_ih1 = (const float*)d_in[6];
    const float* W_hh1 = (const float*)d_in[7];
    const float* b_ih1 = (const float*)d_in[8];
    const float* b_hh1 = (const float*)d_in[9];
    const float* fc_w  = (const float*)d_in[10];
    const float* fc_b  = (const float*)d_in[11];
    float* out  = (float*)d_out;
    float* proj = (float*)d_ws;   // 500*64*4 = 128 KB scratch

    proj_kernel<<<VOCAB, 64, 0, stream>>>(emb, W_ih0, b_ih0, proj);
    rnn_kernel<<<BB / RB, 192, 0, stream>>>(x, proj, W_hh0, b_hh0,
                                            W_ih1, W_hh1, b_ih1, b_hh1,
                                            fc_w, fc_b, out);
}

// Round 18
// 305.833 us; speedup vs baseline: 1.8092x; 1.8092x over previous
//
#include <hip/hip_runtime.h>
#include <math.h>

#define VOCAB 500
#define EMB   64
#define HID   64
#define BB    512
#define TT    512
#define KC    8            // steps per chunk (barrier period)
#define NC    (TT / KC)    // 64 chunks

// tanh(x) = sign(x) * (1 - 2e/(1+e)), e = exp(-2|x|)  (stable, ~1e-6 abs err)
__device__ __forceinline__ float fast_tanh(float x) {
    float ax = fabsf(x);
    float e  = __expf(-2.0f * ax);
    float r  = __builtin_amdgcn_rcpf(1.0f + e);
    float t  = fmaf(-2.0f * e, r, 1.0f);
    return copysignf(t, x);
}

// in-wave broadcast of lane `lane`'s value (compile-time lane) via v_readlane
__device__ __forceinline__ float bcast(float v, int lane) {
    return __int_as_float(__builtin_amdgcn_readlane(__float_as_int(v), lane));
}

// proj[v][j] = b_ih0[j] + sum_k W_ih0[j][k] * emb[v][k]
__global__ __launch_bounds__(64) void proj_kernel(
        const float* __restrict__ emb,
        const float* __restrict__ W_ih0,
        const float* __restrict__ b_ih0,
        float* __restrict__ proj) {
    const int v = blockIdx.x;
    const int j = threadIdx.x;
    const float4* e4 = (const float4*)(emb + v * EMB);
    const float4* w4 = (const float4*)(W_ih0 + j * EMB);
    float acc = b_ih0[j];
    #pragma unroll
    for (int k = 0; k < EMB / 4; ++k) {
        float4 e = e4[k];
        float4 w = w4[k];
        acc = fmaf(w.x, e.x, acc);
        acc = fmaf(w.y, e.y, acc);
        acc = fmaf(w.z, e.z, acc);
        acc = fmaf(w.w, e.w, acc);
    }
    proj[v * HID + j] = acc;
}

// 4-wave chunked pipeline, 1 row/block, barrier per KC steps.
//   wave0 (wid0): h1 recurrence chunk c        (readlane self-broadcast)
//   wave1 (wid1): A_lo = W_ih1[:, 0:32) . h1   chunk c-1 (8 b128 LDS reads)
//   wave2 (wid2): A_hi = W_ih1[:,32:64) . h1   chunk c-1
//   wave3 (wid3): h2 recurrence chunk c-2      (A = A_lo + A_hi per lane)
// Ring parities (verified, as R12): w0 W H1R[c&1]; w1/w2 R H1R[(c-1)&1],
// W AA*[(c-1)&1]; w3 R AA*[c&1] (== (c-2)&1).
__global__ __launch_bounds__(256, 1) void rnn_kernel(
        const int*   __restrict__ x,
        const float* __restrict__ proj,
        const float* __restrict__ W_hh0,
        const float* __restrict__ b_hh0,
        const float* __restrict__ W_ih1,
        const float* __restrict__ W_hh1,
        const float* __restrict__ b_ih1,
        const float* __restrict__ b_hh1,
        const float* __restrict__ fc_w,
        const float* __restrict__ fc_b,
        float* __restrict__ out) {
    const int b   = blockIdx.x;
    const int tid = threadIdx.x;
    const int wid = tid >> 6;          // 0..3 (wave-uniform)
    const int j   = tid & 63;          // hidden unit

    __shared__ __align__(16) float H1R[2][KC][HID];
    __shared__ __align__(16) float AAa[2][KC][HID];
    __shared__ __align__(16) float AAb[2][KC][HID];
    __shared__ int xls[TT];

    // stage this row's token indices into LDS
    for (int t = tid; t < TT; t += 256) xls[t] = x[b * TT + t];

    // weight rows -> registers. Uniform 64-float load for all waves (VGPR
    // allocation is per-kernel anyway); wid1 uses w[0..31], wid2 w[32..63].
    const float* wsrc =
        (wid == 0) ? (W_hh0 + j * HID) :
        (wid == 3) ? (W_hh1 + j * HID) : (W_ih1 + j * HID);
    float w[HID];
    {
        const float4* w4 = (const float4*)wsrc;
        #pragma unroll
        for (int k = 0; k < HID / 4; ++k) {
            float4 t4 = w4[k];
            w[4*k+0] = t4.x; w[4*k+1] = t4.y; w[4*k+2] = t4.z; w[4*k+3] = t4.w;
        }
    }
    // pin: forbid re-loading inside the time loop
    #pragma unroll
    for (int k = 0; k < HID; ++k) asm volatile("" : "+v"(w[k]));

    const float bh0 = b_hh0[j];
    const float bi1 = b_ih1[j] + b_hh1[j];
    const float fcw = fc_w[j];

    __syncthreads();   // xls visible

    float h1reg = 0.0f, h2reg = 0.0f;
    float xin[KC], xinN[KC];
    if (wid == 0) {
        #pragma unroll
        for (int u = 0; u < KC; ++u) xin[u] = proj[xls[u] * HID + j];
    }

    for (int c = 0; c < NC + 2; ++c) {
        if (wid == 0) {
            if (c < NC) {
                const int base = ((c + 1) & (NC - 1)) * KC;
                #pragma unroll
                for (int u = 0; u < KC; ++u)
                    xinN[u] = proj[xls[base + u] * HID + j];

                #pragma unroll
                for (int u = 0; u < KC; ++u) {
                    float a0 = xin[u] + bh0, a1 = 0.0f, a2 = 0.0f, a3 = 0.0f;
                    #pragma unroll
                    for (int k = 0; k < HID; k += 4) {
                        a0 = fmaf(w[k+0], bcast(h1reg, k+0), a0);
                        a1 = fmaf(w[k+1], bcast(h1reg, k+1), a1);
                        a2 = fmaf(w[k+2], bcast(h1reg, k+2), a2);
                        a3 = fmaf(w[k+3], bcast(h1reg, k+3), a3);
                    }
                    h1reg = fast_tanh((a0 + a1) + (a2 + a3));
                    H1R[c & 1][u][j] = h1reg;
                    xin[u] = xinN[u];
                }
            }
        } else if (wid == 1) {
            if (c >= 1 && c <= NC) {
                const int p = (c - 1) & 1;
                #pragma unroll
                for (int u = 0; u < KC; ++u) {
                    const float4* hv = (const float4*)(&H1R[p][u][0]);
                    float a0 = 0.0f, a1 = 0.0f, a2 = 0.0f, a3 = 0.0f;
                    #pragma unroll
                    for (int k = 0; k < 8; ++k) {        // k-half [0,32)
                        float4 h = hv[k];                // uniform -> broadcast
                        a0 = fmaf(w[4*k+0], h.x, a0);
                        a1 = fmaf(w[4*k+1], h.y, a1);
                        a2 = fmaf(w[4*k+2], h.z, a2);
                        a3 = fmaf(w[4*k+3], h.w, a3);
                    }
                    AAa[p][u][j] = (a0 + a1) + (a2 + a3);
                }
            }
        } else if (wid == 2) {
            if (c >= 1 && c <= NC) {
                const int p = (c - 1) & 1;
                #pragma unroll
                for (int u = 0; u < KC; ++u) {
                    const float4* hv = (const float4*)(&H1R[p][u][0]);
                    float a0 = 0.0f, a1 = 0.0f, a2 = 0.0f, a3 = 0.0f;
                    #pragma unroll
                    for (int k = 8; k < 16; ++k) {       // k-half [32,64)
                        float4 h = hv[k];
                        a0 = fmaf(w[4*k+0], h.x, a0);    // w[32..63]
                        a1 = fmaf(w[4*k+1], h.y, a1);
                        a2 = fmaf(w[4*k+2], h.z, a2);
                        a3 = fmaf(w[4*k+3], h.w, a3);
                    }
                    AAb[p][u][j] = (a0 + a1) + (a2 + a3);
                }
            }
        } else {
            if (c >= 2) {
                const int p = c & 1;        // == (c-2)&1
                #pragma unroll
                for (int u = 0; u < KC; ++u) {
                    float a0 = (AAa[p][u][j] + AAb[p][u][j]) + bi1;
                    float a1 = 0.0f, a2 = 0.0f, a3 = 0.0f;
                    #pragma unroll
                    for (int k = 0; k < HID; k += 4) {
                        a0 = fmaf(w[k+0], bcast(h2reg, k+0), a0);
                        a1 = fmaf(w[k+1], bcast(h2reg, k+1), a1);
                        a2 = fmaf(w[k+2], bcast(h2reg, k+2), a2);
                        a3 = fmaf(w[k+3], bcast(h2reg, k+3), a3);
                    }
                    h2reg = fast_tanh((a0 + a1) + (a2 + a3));
                }
            }
        }
        __syncthreads();
    }

    // out[b] = fc_b + sum_j h2[TT-1][j] * fc_w[j]   (wave3 holds h2reg)
    if (wid == 3) {
        float val = h2reg * fcw;
        #pragma unroll
        for (int o = 32; o > 0; o >>= 1) val += __shfl_down(val, o, 64);
        if (j == 0) out[b] = val + fc_b[0];
    }
}

extern "C" void kernel_launch(void* const* d_in, const int* in_sizes, int n_in,
                              void* d_out, int out_size, void* d_ws, size_t ws_size,
                              hipStream_t stream) {
    const int*   x     = (const int*)  d_in[0];
    const float* emb   = (const float*)d_in[1];
    const float* W_ih0 = (const float*)d_in[2];
    const float* W_hh0 = (const float*)d_in[3];
    const float* b_ih0 = (const float*)d_in[4];
    const float* b_hh0 = (const float*)d_in[5];
    const float* W_ih1 = (const float*)d_in[6];
    const float* W_hh1 = (const float*)d_in[7];
    const float* b_ih1 = (const float*)d_in[8];
    const float* b_hh1 = (const float*)d_in[9];
    const float* fc_w  = (const float*)d_in[10];
    const float* fc_b  = (const float*)d_in[11];
    float* out  = (float*)d_out;
    float* proj = (float*)d_ws;   // 500*64*4 = 128 KB scratch

    proj_kernel<<<VOCAB, 64, 0, stream>>>(emb, W_ih0, b_ih0, proj);
    rnn_kernel<<<BB, 256, 0, stream>>>(x, proj, W_hh0, b_hh0,
                                       W_ih1, W_hh1, b_ih1, b_hh1,
                                       fc_w, fc_b, out);
}